// Round 3
// baseline (76.070 us; speedup 1.0000x reference)
//
#include <hip/hip_runtime.h>

#define N_TASKS 16
#define LMAX 64
#define LDS_STRIDE 68  // 68%32=4 -> tasks staggered across banks; 272B row keeps 16B alignment

typedef float f32x4 __attribute__((ext_vector_type(4)));

__global__ __launch_bounds__(256) void MultiElementWiseAffine_kernel(
    const float* __restrict__ input,      // [B]
    const int*   __restrict__ task_ids,   // [B]
    const float* __restrict__ offsets,    // [N_TASKS*LMAX]
    const float* __restrict__ disc,       // [N_TASKS*LMAX]
    const int*   __restrict__ lengths,    // [N_TASKS]
    f32x4*       __restrict__ out,        // [B*16] float4 view of [B][64]
    int total_pairs)                      // B*8  (one pair = 2 consecutive float4s)
{
    __shared__ alignas(16) float s_off[N_TASKS * LDS_STRIDE];
    __shared__ alignas(16) float s_mdisc[N_TASKS * LDS_STRIDE];

    // Stage tables; fold the validity mask into the discrimination table.
    for (int i = threadIdx.x; i < N_TASKS * LMAX; i += blockDim.x) {
        int t = i >> 6;          // task
        int k = i & (LMAX - 1);  // threshold index
        s_off[t * LDS_STRIDE + k]   = offsets[i];
        s_mdisc[t * LDS_STRIDE + k] = (k < lengths[t]) ? disc[i] : 0.0f;
    }
    __syncthreads();

    const int stride = gridDim.x * blockDim.x;
    for (int p = blockIdx.x * blockDim.x + threadIdx.x; p < total_pairs; p += stride) {
        int row = p >> 3;   // 8 pairs (of float4s) per 64-float row
        int k8  = p & 7;    // which 8-float chunk within the row
        int t   = task_ids[row];
        float x = input[row];
        const float* o = &s_off[t * LDS_STRIDE + (k8 << 3)];
        const float* m = &s_mdisc[t * LDS_STRIDE + (k8 << 3)];
        f32x4 o0 = *(const f32x4*)(o);
        f32x4 o1 = *(const f32x4*)(o + 4);
        f32x4 m0 = *(const f32x4*)(m);
        f32x4 m1 = *(const f32x4*)(m + 4);
        f32x4 r0, r1;
        r0.x = m0.x * (x + o0.x);  r0.y = m0.y * (x + o0.y);
        r0.z = m0.z * (x + o0.z);  r0.w = m0.w * (x + o0.w);
        r1.x = m1.x * (x + o1.x);  r1.y = m1.y * (x + o1.y);
        r1.z = m1.z * (x + o1.z);  r1.w = m1.w * (x + o1.w);
        out[2 * p]     = r0;
        out[2 * p + 1] = r1;
    }
}

extern "C" void kernel_launch(void* const* d_in, const int* in_sizes, int n_in,
                              void* d_out, int out_size, void* d_ws, size_t ws_size,
                              hipStream_t stream) {
    const float* input    = (const float*)d_in[0];
    const int*   task_ids = (const int*)d_in[1];
    const float* offsets  = (const float*)d_in[2];
    const float* disc     = (const float*)d_in[3];
    const int*   lengths  = (const int*)d_in[4];
    f32x4*       out      = (f32x4*)d_out;

    int total_pairs = out_size / 8;      // B * 8
    int block  = 256;
    int grid   = 2048;                   // 524288 threads, 16 pair-iterations each

    MultiElementWiseAffine_kernel<<<grid, block, 0, stream>>>(
        input, task_ids, offsets, disc, lengths, out, total_pairs);
}

// Round 4
// 56.547 us; speedup vs baseline: 1.3452x; 1.3452x over previous
//
#include <hip/hip_runtime.h>

#define N_TASKS 16
#define LMAX 64
#define LDS_STRIDE 68  // 68%32=4 -> tasks staggered across banks; 272B row keeps 16B alignment

typedef float f32x4 __attribute__((ext_vector_type(4)));

__global__ __launch_bounds__(256) void MultiElementWiseAffine_kernel(
    const float* __restrict__ input,      // [B]
    const int*   __restrict__ task_ids,   // [B]
    const float* __restrict__ offsets,    // [N_TASKS*LMAX]
    const float* __restrict__ disc,       // [N_TASKS*LMAX]
    const int*   __restrict__ lengths,    // [N_TASKS]
    f32x4*       __restrict__ out,        // [B*16] float4 view of [B][64]
    int total4)                           // B*16
{
    __shared__ alignas(16) float s_off[N_TASKS * LDS_STRIDE];
    __shared__ alignas(16) float s_mdisc[N_TASKS * LDS_STRIDE];

    // Stage tables; fold the validity mask into the discrimination table.
    for (int i = threadIdx.x; i < N_TASKS * LMAX; i += blockDim.x) {
        int t = i >> 6;          // task
        int k = i & (LMAX - 1);  // threshold index
        s_off[t * LDS_STRIDE + k]   = offsets[i];
        s_mdisc[t * LDS_STRIDE + k] = (k < lengths[t]) ? disc[i] : 0.0f;
    }
    __syncthreads();

    const int stride = gridDim.x * blockDim.x;
    int g = blockIdx.x * blockDim.x + threadIdx.x;
    if (g >= total4) return;

    // Prime the pipeline: this iteration's row data.
    int   t_cur = task_ids[g >> 4];
    float x_cur = input[g >> 4];

    for (; g < total4; g += stride) {
        // Issue NEXT iteration's gather now; it resolves under this
        // iteration's LDS reads + FMAs + store. Clamp keeps it in-bounds.
        int gn    = g + stride;
        int rown  = (gn < total4 ? gn : g) >> 4;
        int t_nxt = task_ids[rown];
        float x_nxt = input[rown];

        int k4 = g & 15;
        const float* o = &s_off[t_cur * LDS_STRIDE + (k4 << 2)];
        const float* m = &s_mdisc[t_cur * LDS_STRIDE + (k4 << 2)];
        f32x4 ov = *(const f32x4*)o;
        f32x4 mv = *(const f32x4*)m;
        f32x4 r;
        r.x = mv.x * (x_cur + ov.x);
        r.y = mv.y * (x_cur + ov.y);
        r.z = mv.z * (x_cur + ov.z);
        r.w = mv.w * (x_cur + ov.w);
        out[g] = r;   // lane-dense: 1 KB contiguous per wave store instruction

        t_cur = t_nxt;
        x_cur = x_nxt;
    }
}

extern "C" void kernel_launch(void* const* d_in, const int* in_sizes, int n_in,
                              void* d_out, int out_size, void* d_ws, size_t ws_size,
                              hipStream_t stream) {
    const float* input    = (const float*)d_in[0];
    const int*   task_ids = (const int*)d_in[1];
    const float* offsets  = (const float*)d_in[2];
    const float* disc     = (const float*)d_in[3];
    const int*   lengths  = (const int*)d_in[4];
    f32x4*       out      = (f32x4*)d_out;

    int total4 = out_size / 4;           // B * 16
    int block  = 256;
    int grid   = 2048;                   // exactly-resident: 8 blocks/CU, 32 iters/thread

    MultiElementWiseAffine_kernel<<<grid, block, 0, stream>>>(
        input, task_ids, offsets, disc, lengths, out, total4);
}

// Round 5
// 52.596 us; speedup vs baseline: 1.4463x; 1.0751x over previous
//
#include <hip/hip_runtime.h>

#define N_TASKS 16
#define LMAX 64

typedef float f32x4 __attribute__((ext_vector_type(4)));

__global__ __launch_bounds__(256) void MultiElementWiseAffine_kernel(
    const float* __restrict__ input,      // [B]
    const int*   __restrict__ task_ids,   // [B]
    const float* __restrict__ offsets,    // [N_TASKS*LMAX]
    const float* __restrict__ disc,       // [N_TASKS*LMAX]
    const int*   __restrict__ lengths,    // [N_TASKS]
    f32x4*       __restrict__ out,        // [B*16] float4 view of [B][64]
    int total4)                           // B*16
{
    // Interleaved per-task table: [t][0..63] = masked disc (m), [t][64..127] = m*o.
    // Row stride 128 floats = 512B -> one LDS base per iter, second read at offset:256.
    __shared__ alignas(16) float s_tab[N_TASKS * 2 * LMAX];

    for (int i = threadIdx.x; i < N_TASKS * LMAX; i += blockDim.x) {
        int t = i >> 6;          // task
        int k = i & (LMAX - 1);  // threshold index
        float m = (k < lengths[t]) ? disc[i] : 0.0f;
        s_tab[t * 128 + k]      = m;
        s_tab[t * 128 + 64 + k] = m * offsets[i];
    }
    __syncthreads();

    const int stride = gridDim.x * blockDim.x;
    int g = blockIdx.x * blockDim.x + threadIdx.x;
    if (g >= total4) return;

    // 2-stage pipeline: prefetch next iteration's row data (neutral-to-positive, keep).
    int   t_cur = task_ids[g >> 4];
    float x_cur = input[g >> 4];

    for (; g < total4; g += stride) {
        int gn      = g + stride;
        int rown    = (gn < total4 ? gn : g) >> 4;
        int t_nxt   = task_ids[rown];
        float x_nxt = input[rown];

        int k4 = g & 15;
        const float* base = &s_tab[t_cur * 128 + (k4 << 2)];
        f32x4 mv = *(const f32x4*)(base);       // ds_read_b128 offset:0
        f32x4 pv = *(const f32x4*)(base + 64);  // ds_read_b128 offset:256
        f32x4 r;
        r.x = fmaf(mv.x, x_cur, pv.x);
        r.y = fmaf(mv.y, x_cur, pv.y);
        r.z = fmaf(mv.z, x_cur, pv.z);
        r.w = fmaf(mv.w, x_cur, pv.w);
        // Lane-dense (lane i -> base+16B*i), non-temporal: write-once stream.
        __builtin_nontemporal_store(r, &out[g]);

        t_cur = t_nxt;
        x_cur = x_nxt;
    }
}

extern "C" void kernel_launch(void* const* d_in, const int* in_sizes, int n_in,
                              void* d_out, int out_size, void* d_ws, size_t ws_size,
                              hipStream_t stream) {
    const float* input    = (const float*)d_in[0];
    const int*   task_ids = (const int*)d_in[1];
    const float* offsets  = (const float*)d_in[2];
    const float* disc     = (const float*)d_in[3];
    const int*   lengths  = (const int*)d_in[4];
    f32x4*       out      = (f32x4*)d_out;

    int total4 = out_size / 4;           // B * 16
    int block  = 256;
    int grid   = 2048;                   // 8 blocks/CU, 32 iters/thread

    MultiElementWiseAffine_kernel<<<grid, block, 0, stream>>>(
        input, task_ids, offsets, disc, lengths, out, total4);
}